// Round 9
// baseline (102.087 us; speedup 1.0000x reference)
//
#include <hip/hip_runtime.h>
#include <stdint.h>

#define B_ROWS 16384
#define C_CLS  2000
#define C_PAD  2048
#define F_DIM  1024
#define KT     16                         // K-tiles of 64
#define NRB    64                         // gemm row blocks (256 rows)
#define NCB    8                          // gemm col blocks (256 cols)
#define TILE8  16384                      // bytes per 256x64 fp8 tile image (A or B)
#define PANEL_B ((size_t)KT * TILE8)      // 256 KB per 256-row/col panel

typedef float f32x4 __attribute__((ext_vector_type(4)));
typedef long long i64x2 __attribute__((ext_vector_type(2)));

#define SCALE_F 4.0f
#define SCALE_W 16.0f
#define INV_SCALE 0.015625f               // 1/64

__device__ __forceinline__ void gl_lds16(const void* g, void* l) {
    __builtin_amdgcn_global_load_lds(
        (const __attribute__((address_space(1))) unsigned int*)g,
        (__attribute__((address_space(3))) unsigned int*)l, 16, 0, 0);
}

__device__ __forceinline__ unsigned int pk4(float a, float b, float c, float d) {
    int u = __builtin_amdgcn_cvt_pk_fp8_f32(a, b, 0, false);   // bytes 0,1
    u = __builtin_amdgcn_cvt_pk_fp8_f32(c, d, u, true);        // bytes 2,3
    return (unsigned int)u;
}

// Tile image (16KB = 256 rows x 64 k fp8): line j(0..127) of 128B; 16B slot
// t = rh*4 + lhi (rh = row>=128) at byte ((t ^ (j&7))<<4); slot = [kf0: k=lhi*8..+8][kf1: k=32+lhi*8..+8].
// GEMM read key (wr*4+lhi)^(l15&7) == measured-conflict-free pattern (R7/R8: 16K).

// ---- prepass A: feat -> fp8 images (x4), fused fisher. grid 512 = rt(128) x g(4) ----
__global__ __launch_bounds__(256)
void prepA_kernel(const float* __restrict__ feat, const int* __restrict__ labels,
                  const float* __restrict__ centers,
                  char* __restrict__ A_pre, float* __restrict__ fisher_part)
{
    const int rt = blockIdx.x >> 2, g = blockIdx.x & 3;
    const int rb = rt >> 1, rh = rt & 1;
    const int tid = threadIdx.x;
    const int r = tid >> 1, h = tid & 1;
    const int grow = rt * 128 + r;
    const int lab = labels[grow];
    const float* frow = feat    + (size_t)grow * F_DIM;
    const float* crow = centers + (size_t)lab  * F_DIM;
    char* dbase = A_pre + (size_t)rb * PANEL_B + r * 128;
    float facc = 0.f;
    #pragma unroll
    for (int q = 0; q < 4; ++q) {
        const int kt = g * 4 + q;
        char* dst = dbase + kt * TILE8;
        #pragma unroll
        for (int u = 0; u < 2; ++u) {
            const int lhi = h * 2 + u;
            const int k0 = kt * 64 + lhi * 8;
            float4 a0 = *(const float4*)(frow + k0);
            float4 a1 = *(const float4*)(frow + k0 + 4);
            float4 a2 = *(const float4*)(frow + k0 + 32);
            float4 a3 = *(const float4*)(frow + k0 + 36);
            float4 c0 = *(const float4*)(crow + k0);
            float4 c1 = *(const float4*)(crow + k0 + 4);
            float4 c2 = *(const float4*)(crow + k0 + 32);
            float4 c3 = *(const float4*)(crow + k0 + 36);
            float d0 = a0.x-c0.x, d1 = a0.y-c0.y, d2 = a0.z-c0.z, d3 = a0.w-c0.w;
            float d4 = a1.x-c1.x, d5 = a1.y-c1.y, d6 = a1.z-c1.z, d7 = a1.w-c1.w;
            facc += d0*d0 + d1*d1 + d2*d2 + d3*d3 + d4*d4 + d5*d5 + d6*d6 + d7*d7;
            d0 = a2.x-c2.x; d1 = a2.y-c2.y; d2 = a2.z-c2.z; d3 = a2.w-c2.w;
            d4 = a3.x-c3.x; d5 = a3.y-c3.y; d6 = a3.z-c3.z; d7 = a3.w-c3.w;
            facc += d0*d0 + d1*d1 + d2*d2 + d3*d3 + d4*d4 + d5*d5 + d6*d6 + d7*d7;
            uint4 o = { pk4(SCALE_F*a0.x, SCALE_F*a0.y, SCALE_F*a0.z, SCALE_F*a0.w),
                        pk4(SCALE_F*a1.x, SCALE_F*a1.y, SCALE_F*a1.z, SCALE_F*a1.w),
                        pk4(SCALE_F*a2.x, SCALE_F*a2.y, SCALE_F*a2.z, SCALE_F*a2.w),
                        pk4(SCALE_F*a3.x, SCALE_F*a3.y, SCALE_F*a3.z, SCALE_F*a3.w) };
            const int t = rh * 4 + lhi;
            *(uint4*)(dst + ((t ^ (r & 7)) << 4)) = o;
        }
    }
    for (int d = 32; d >= 1; d >>= 1) facc += __shfl_xor(facc, d);
    __shared__ float redw[4];
    const int wid = tid >> 6, lane = tid & 63;
    if (lane == 0) redw[wid] = facc;
    __syncthreads();
    if (tid == 0) fisher_part[blockIdx.x] = redw[0] + redw[1] + redw[2] + redw[3];
}

// ---- prepass B: W -> fp8 images (x16), zero-pad; bias pad folded. grid 128 = ct(16) x ktg(8) ----
__global__ __launch_bounds__(256)
void prepB_kernel(const float* __restrict__ W, const float* __restrict__ bias,
                  char* __restrict__ B_pre, float* __restrict__ bias_pad)
{
    const int ct = blockIdx.x >> 3, ktg = blockIdx.x & 7;
    const int cb = ct >> 1, rh = ct & 1;
    const int tid = threadIdx.x;
    const int rcol = tid >> 1, h = tid & 1;
    const int gc = ct * 128 + rcol;
    char* dbase = B_pre + (size_t)cb * PANEL_B + rcol * 128;
    #pragma unroll
    for (int q = 0; q < 2; ++q) {
        const int kt = ktg * 2 + q;
        char* dst = dbase + kt * TILE8;
        #pragma unroll
        for (int u = 0; u < 2; ++u) {
            const int lhi = h * 2 + u;
            const int t = rh * 4 + lhi;
            uint4 o;
            if (gc < C_CLS) {
                const float* src = W + (size_t)gc * F_DIM + kt * 64 + lhi * 8;
                float4 a0 = *(const float4*)(src);
                float4 a1 = *(const float4*)(src + 4);
                float4 a2 = *(const float4*)(src + 32);
                float4 a3 = *(const float4*)(src + 36);
                o = (uint4){ pk4(SCALE_W*a0.x, SCALE_W*a0.y, SCALE_W*a0.z, SCALE_W*a0.w),
                             pk4(SCALE_W*a1.x, SCALE_W*a1.y, SCALE_W*a1.z, SCALE_W*a1.w),
                             pk4(SCALE_W*a2.x, SCALE_W*a2.y, SCALE_W*a2.z, SCALE_W*a2.w),
                             pk4(SCALE_W*a3.x, SCALE_W*a3.y, SCALE_W*a3.z, SCALE_W*a3.w) };
            } else {
                o = (uint4){0u, 0u, 0u, 0u};
            }
            *(uint4*)(dst + ((t ^ (rcol & 7)) << 4)) = o;
        }
    }
    if (blockIdx.x < C_PAD / 256) {
        const int i = blockIdx.x * 256 + tid;
        bias_pad[i] = (i < C_CLS) ? bias[i] : -1e30f;
    }
}

// ---- 256x256 fp8 MFMA GEMM, 2-phase/K-tile + register read-ahead pipeline ----
// LDS: 3 bufs x (A 16KB + B 16KB) = 96 KB; epilogue red2 reuses buffer space.
__global__ __launch_bounds__(512, 2)
void gemm_kernel(const int* __restrict__ labels, const float* __restrict__ biasp,
                 const char* __restrict__ A_pre, const char* __restrict__ B_pre,
                 float* __restrict__ s_part, float* __restrict__ tl_part)
{
    __shared__ alignas(128) char smem[98304];

    const int cpx = gridDim.x >> 3;                 // XCD swizzle: same-XCD blocks share rb
    const int wg = (blockIdx.x & 7) * cpx + (blockIdx.x >> 3);
    const int cb = wg & 7;
    const int rb = wg >> 3;

    const int tid = threadIdx.x;
    const int w = tid >> 6, lane = tid & 63;
    const int l15 = lane & 15, lhi = lane >> 4;
    const int wr = w >> 2, wc = w & 3;

    const char* Asrc = A_pre + (size_t)rb * PANEL_B;
    const char* Bsrc = B_pre + (size_t)cb * PANEL_B;

    // conflict-free swizzled ds_read_b128 bases (fragment mi/ni at base + idx*2048)
    const int abase = l15 * 128 + (((wr * 4 + lhi) ^ (l15 & 7)) << 4);
    const int bbase = 16384 + (wc & 1) * 8192 + l15 * 128
                    + ((((wc >> 1) * 4 + lhi) ^ (l15 & 7)) << 4);

    f32x4 acc[8][4];
    #pragma unroll
    for (int mi = 0; mi < 8; ++mi)
        #pragma unroll
        for (int ni = 0; ni < 4; ++ni) acc[mi][ni] = (f32x4){0.f, 0.f, 0.f, 0.f};

    const int woff = w * 1024;
    i64x2 fE_a[8], fE_b[4], fO_a[8], fO_b[4];   // register-double-buffered fragments

#define STAGEQ(SRCQ, LOFF) gl_lds16((SRCQ) + tid * 16, smem + (LOFF) + woff)
#define FENCE __builtin_amdgcn_sched_barrier(0)
#define WAITV(N) asm volatile("s_waitcnt vmcnt(" #N ")" ::: "memory")
#define WAITL0  asm volatile("s_waitcnt lgkmcnt(0)" ::: "memory")
#define BAR __builtin_amdgcn_s_barrier()

#define MFMA32(SET, KF) do {                                                          \
    __builtin_amdgcn_s_setprio(1);                                                    \
    _Pragma("unroll")                                                                 \
    for (int mi_ = 0; mi_ < 8; ++mi_)                                                 \
        _Pragma("unroll")                                                             \
        for (int ni_ = 0; ni_ < 4; ++ni_)                                             \
            acc[mi_][ni_] = __builtin_amdgcn_mfma_f32_16x16x32_fp8_fp8(               \
                SET##_a[mi_][KF], SET##_b[ni_][KF], acc[mi_][ni_], 0, 0, 0);          \
    __builtin_amdgcn_s_setprio(0);                                                    \
} while (0)

#define READF(SET, NB) do {                                                           \
    _Pragma("unroll")                                                                 \
    for (int ni_ = 0; ni_ < 4; ++ni_)                                                 \
        SET##_b[ni_] = *(const i64x2*)((NB) + bbase + ni_ * 2048);                    \
    _Pragma("unroll")                                                                 \
    for (int mi_ = 0; mi_ < 8; ++mi_)                                                 \
        SET##_a[mi_] = *(const i64x2*)((NB) + abase + mi_ * 2048);                    \
} while (0)

// One K-tile: P0 {stage A-half of kt+3, MFMA kf0, counted vmcnt gate, bar};
//             P1 {read kt+1 frags, stage B-half, MFMA kf1, drain reads, bar}
#define TILE_STEP(CUR, NXT, DOSTG, SRC_A, SRC_B, DOREAD, WTN, DOBAR) do {             \
    if (DOSTG) { STAGEQ(SRC_A, bo); STAGEQ((SRC_A) + 8192, bo + 8192); }              \
    FENCE;                                                                            \
    MFMA32(CUR, 0);                                                                   \
    FENCE;                                                                            \
    WAITV(WTN);                                                                       \
    FENCE;                                                                            \
    BAR;                                                                              \
    if (DOREAD) { READF(NXT, smem + bn); }                                            \
    FENCE;                                                                            \
    if (DOSTG) { STAGEQ(SRC_B, bo + 16384); STAGEQ((SRC_B) + 8192, bo + 24576); }     \
    FENCE;                                                                            \
    MFMA32(CUR, 1);                                                                   \
    FENCE;                                                                            \
    WAITL0;                                                                           \
    FENCE;                                                                            \
    if (DOBAR) { BAR; }                                                               \
    bo = bn; bn = (bn == 65536) ? 0 : bn + 32768;                                     \
} while (0)

    // prologue: tiles 0,1,2 -> bufs 0,1,2 (A lo/hi, B lo/hi each)
    #pragma unroll
    for (int t = 0; t < 3; ++t) {
        STAGEQ(Asrc + t * TILE8,        t * 32768);
        STAGEQ(Asrc + t * TILE8 + 8192, t * 32768 + 8192);
        STAGEQ(Bsrc + t * TILE8,        t * 32768 + 16384);
        STAGEQ(Bsrc + t * TILE8 + 8192, t * 32768 + 24576);
    }
    WAITV(8);           // tile 0 resident
    FENCE;
    BAR;
    int bo = 0, bn = 32768;
    READF(fE, smem);    // tile 0 fragments
    FENCE;

    #pragma unroll 1
    for (int kt = 0; kt < 12; kt += 2) {
        const char* sA0 = Asrc + (size_t)(kt + 3) * TILE8;
        const char* sB0 = Bsrc + (size_t)(kt + 3) * TILE8;
        TILE_STEP(fE, fO, true, sA0, sB0, true, 6, true);
        const char* sA1 = Asrc + (size_t)(kt + 4) * TILE8;
        const char* sB1 = Bsrc + (size_t)(kt + 4) * TILE8;
        TILE_STEP(fO, fE, true, sA1, sB1, true, 6, true);
    }
    // tail: kt=12 (stage tile15), 13, 14, 15
    TILE_STEP(fE, fO, true,  Asrc + 15 * TILE8, Bsrc + 15 * TILE8, true, 6, true);
    TILE_STEP(fO, fE, false, Asrc, Bsrc, true, 4, true);
    TILE_STEP(fE, fO, false, Asrc, Bsrc, true, 0, true);
    MFMA32(fO, 0);
    MFMA32(fO, 1);

#undef TILE_STEP
#undef READF
#undef MFMA32
#undef STAGEQ
#undef FENCE
#undef WAITV
#undef WAITL0
#undef BAR

    // epilogue: rescale + direct sum-exp; red2 reuses the staging LDS
    __syncthreads();
    float (*red2)[4][2] = (float (*)[4][2])smem;

    float bb[4];
    #pragma unroll
    for (int ni = 0; ni < 4; ++ni)
        bb[ni] = biasp[cb * 256 + wc * 64 + ni * 16 + l15];

    #pragma unroll
    for (int mi = 0; mi < 8; ++mi) {
        #pragma unroll
        for (int j = 0; j < 4; ++j) {
            const int rl = wr * 128 + mi * 16 + lhi * 4 + j;
            const int lab = labels[rb * 256 + rl];
            float sv = 0.f, tv = 0.f;
            #pragma unroll
            for (int ni = 0; ni < 4; ++ni) {
                const float v = fmaf(acc[mi][ni][j], INV_SCALE, bb[ni]);
                sv += __expf(v);
                const int gc = cb * 256 + wc * 64 + ni * 16 + l15;
                tv = (gc == lab) ? v : tv;
            }
            #pragma unroll
            for (int d = 1; d < 16; d <<= 1) {
                sv += __shfl_xor(sv, d);
                tv += __shfl_xor(tv, d);
            }
            if (l15 == 0) { red2[rl][wc][0] = sv; red2[rl][wc][1] = tv; }
        }
    }
    __syncthreads();
    if (tid < 256) {
        const float sv = red2[tid][0][0] + red2[tid][1][0] + red2[tid][2][0] + red2[tid][3][0];
        const float tv = red2[tid][0][1] + red2[tid][1][1] + red2[tid][2][1] + red2[tid][3][1];
        const int grow = rb * 256 + tid;
        s_part[(size_t)cb * B_ROWS + grow]  = sv;
        tl_part[(size_t)cb * B_ROWS + grow] = tv;
    }
}

// ---- combine partials across the 8 column blocks, per-row aux loss ----
__global__ __launch_bounds__(256)
void rowcomb_kernel(const float* __restrict__ s_part, const float* __restrict__ tl_part,
                    float* __restrict__ aux_part)
{
    const int row = blockIdx.x * 256 + threadIdx.x;
    float s = 0.f, t = 0.f;
    #pragma unroll
    for (int p = 0; p < NCB; ++p) {
        s += s_part[(size_t)p * B_ROWS + row];
        t += tl_part[(size_t)p * B_ROWS + row];
    }
    float acc = __logf(s) - t;
    for (int d = 32; d >= 1; d >>= 1) acc += __shfl_xor(acc, d);
    __shared__ float red[4];
    const int wid = threadIdx.x >> 6, lane = threadIdx.x & 63;
    if (lane == 0) red[wid] = acc;
    __syncthreads();
    if (threadIdx.x == 0) aux_part[blockIdx.x] = red[0] + red[1] + red[2] + red[3];
}

__global__ __launch_bounds__(256)
void final_kernel(const float* __restrict__ fisher_part, const float* __restrict__ aux_part,
                  float* __restrict__ out)
{
    const int tid = threadIdx.x;
    float acc = fisher_part[tid] + fisher_part[256 + tid];
    if (tid < 64) acc += aux_part[tid];
    for (int d = 32; d >= 1; d >>= 1) acc += __shfl_xor(acc, d);
    __shared__ float red[4];
    const int wid = tid >> 6, lane = tid & 63;
    if (lane == 0) red[wid] = acc;
    __syncthreads();
    if (tid == 0) out[0] = (red[0] + red[1] + red[2] + red[3]) * (1.0f / (float)B_ROWS);
}

extern "C" void kernel_launch(void* const* d_in, const int* in_sizes, int n_in,
                              void* d_out, int out_size, void* d_ws, size_t ws_size,
                              hipStream_t stream)
{
    (void)in_sizes; (void)n_in; (void)out_size; (void)ws_size;
    const float* feat    = (const float*)d_in[0];
    const int*   labels  = (const int*)  d_in[1];
    const float* centers = (const float*)d_in[2];
    const float* W       = (const float*)d_in[3];
    const float* bias    = (const float*)d_in[4];
    float* out = (float*)d_out;
    char* ws = (char*)d_ws;

    const size_t szA    = (size_t)NRB * PANEL_B;   // 16,777,216
    const size_t szB    = (size_t)NCB * PANEL_B;   //  2,097,152
    const size_t szBias = (size_t)C_PAD * 4;

    char* A_pre = ws;
    char* B_pre = ws + szA;
    float* bias_pad    = (float*)(ws + szA + szB);
    float* s_part      = (float*)(ws + szA + szB + szBias);
    float* tl_part     = s_part + (size_t)NCB * B_ROWS;
    float* fisher_part = tl_part + (size_t)NCB * B_ROWS;
    float* aux_part    = fisher_part + 512;

    prepA_kernel<<<512, 256, 0, stream>>>(feat, labels, centers, A_pre, fisher_part);
    prepB_kernel<<<128, 256, 0, stream>>>(W, bias, B_pre, bias_pad);
    gemm_kernel<<<NRB * NCB, 512, 0, stream>>>(labels, bias_pad, A_pre, B_pre, s_part, tl_part);
    rowcomb_kernel<<<B_ROWS / 256, 256, 0, stream>>>(s_part, tl_part, aux_part);
    final_kernel<<<1, 256, 0, stream>>>(fisher_part, aux_part, out);
}

// Round 10
// 86.841 us; speedup vs baseline: 1.1756x; 1.1756x over previous
//
#include <hip/hip_runtime.h>
#include <stdint.h>

#define B_ROWS 16384
#define C_CLS  2000
#define C_PAD  2048
#define F_DIM  1024
#define KT     16                         // K-tiles of 64
#define NRB    128                        // gemm row blocks (128 rows)
#define NCBP   16                         // gemm col panels (128 cols)
#define PANEL_B 131072                    // 16 kt x 8 frags x 1024 B

typedef float f32x4 __attribute__((ext_vector_type(4)));
typedef long long i64x2 __attribute__((ext_vector_type(2)));

#define SCALE_F 4.0f
#define SCALE_W 16.0f
#define INV_SCALE 0.015625f               // 1/64

__device__ __forceinline__ unsigned int pk4(float a, float b, float c, float d) {
    int u = __builtin_amdgcn_cvt_pk_fp8_f32(a, b, 0, false);   // bytes 0,1
    u = __builtin_amdgcn_cvt_pk_fp8_f32(c, d, u, true);        // bytes 2,3
    return (unsigned int)u;
}

// Fragment-linear panel layout: panel + ((kt*8 + f)*1024) + lane*16.
// Lane l of frag f holds rows f*16 + (l&15), 16B = k [lhi*8..+8) ∪ [32+lhi*8..+8)
// (exactly the mfma_f32_16x16x32_fp8 A/B operand; i64x2 = [kf0, kf1]).

// ---- prepass A: feat -> fp8 fragment panels (x4), fused fisher. grid 512 = rt(128) x g(4) ----
__global__ __launch_bounds__(256)
void prepA_kernel(const float* __restrict__ feat, const int* __restrict__ labels,
                  const float* __restrict__ centers,
                  char* __restrict__ A_pre, float* __restrict__ fisher_part)
{
    const int rt = blockIdx.x >> 2, g = blockIdx.x & 3;
    const int tid = threadIdx.x;
    const int r = tid >> 1, h = tid & 1;
    const int grow = rt * 128 + r;
    const int lab = labels[grow];
    const float* frow = feat    + (size_t)grow * F_DIM;
    const float* crow = centers + (size_t)lab  * F_DIM;
    char* pan = A_pre + (size_t)rt * PANEL_B + (r >> 4) * 1024 + (r & 15) * 16;
    float facc = 0.f;
    #pragma unroll
    for (int q = 0; q < 4; ++q) {
        const int kt = g * 4 + q;
        #pragma unroll
        for (int u = 0; u < 2; ++u) {
            const int lhi = h * 2 + u;
            const int k0 = kt * 64 + lhi * 8;
            float4 a0 = *(const float4*)(frow + k0);
            float4 a1 = *(const float4*)(frow + k0 + 4);
            float4 a2 = *(const float4*)(frow + k0 + 32);
            float4 a3 = *(const float4*)(frow + k0 + 36);
            float4 c0 = *(const float4*)(crow + k0);
            float4 c1 = *(const float4*)(crow + k0 + 4);
            float4 c2 = *(const float4*)(crow + k0 + 32);
            float4 c3 = *(const float4*)(crow + k0 + 36);
            float d0 = a0.x-c0.x, d1 = a0.y-c0.y, d2 = a0.z-c0.z, d3 = a0.w-c0.w;
            float d4 = a1.x-c1.x, d5 = a1.y-c1.y, d6 = a1.z-c1.z, d7 = a1.w-c1.w;
            facc += d0*d0 + d1*d1 + d2*d2 + d3*d3 + d4*d4 + d5*d5 + d6*d6 + d7*d7;
            d0 = a2.x-c2.x; d1 = a2.y-c2.y; d2 = a2.z-c2.z; d3 = a2.w-c2.w;
            d4 = a3.x-c3.x; d5 = a3.y-c3.y; d6 = a3.z-c3.z; d7 = a3.w-c3.w;
            facc += d0*d0 + d1*d1 + d2*d2 + d3*d3 + d4*d4 + d5*d5 + d6*d6 + d7*d7;
            uint4 o = { pk4(SCALE_F*a0.x, SCALE_F*a0.y, SCALE_F*a0.z, SCALE_F*a0.w),
                        pk4(SCALE_F*a1.x, SCALE_F*a1.y, SCALE_F*a1.z, SCALE_F*a1.w),
                        pk4(SCALE_F*a2.x, SCALE_F*a2.y, SCALE_F*a2.z, SCALE_F*a2.w),
                        pk4(SCALE_F*a3.x, SCALE_F*a3.y, SCALE_F*a3.z, SCALE_F*a3.w) };
            *(uint4*)(pan + kt * 8192 + lhi * 256) = o;
        }
    }
    for (int d = 32; d >= 1; d >>= 1) facc += __shfl_xor(facc, d);
    __shared__ float redw[4];
    const int wid = tid >> 6, lane = tid & 63;
    if (lane == 0) redw[wid] = facc;
    __syncthreads();
    if (tid == 0) fisher_part[blockIdx.x] = redw[0] + redw[1] + redw[2] + redw[3];
}

// ---- prepass B: W -> fp8 fragment panels (x16), zero-pad; bias pad folded. grid 128 ----
__global__ __launch_bounds__(256)
void prepB_kernel(const float* __restrict__ W, const float* __restrict__ bias,
                  char* __restrict__ B_pre, float* __restrict__ bias_pad)
{
    const int ct = blockIdx.x >> 3, ktg = blockIdx.x & 7;
    const int tid = threadIdx.x;
    const int rcol = tid >> 1, h = tid & 1;
    const int gc = ct * 128 + rcol;
    char* pan = B_pre + (size_t)ct * PANEL_B + (rcol >> 4) * 1024 + (rcol & 15) * 16;
    #pragma unroll
    for (int q = 0; q < 2; ++q) {
        const int kt = ktg * 2 + q;
        #pragma unroll
        for (int u = 0; u < 2; ++u) {
            const int lhi = h * 2 + u;
            uint4 o;
            if (gc < C_CLS) {
                const float* src = W + (size_t)gc * F_DIM + kt * 64 + lhi * 8;
                float4 a0 = *(const float4*)(src);
                float4 a1 = *(const float4*)(src + 4);
                float4 a2 = *(const float4*)(src + 32);
                float4 a3 = *(const float4*)(src + 36);
                o = (uint4){ pk4(SCALE_W*a0.x, SCALE_W*a0.y, SCALE_W*a0.z, SCALE_W*a0.w),
                             pk4(SCALE_W*a1.x, SCALE_W*a1.y, SCALE_W*a1.z, SCALE_W*a1.w),
                             pk4(SCALE_W*a2.x, SCALE_W*a2.y, SCALE_W*a2.z, SCALE_W*a2.w),
                             pk4(SCALE_W*a3.x, SCALE_W*a3.y, SCALE_W*a3.z, SCALE_W*a3.w) };
            } else {
                o = (uint4){0u, 0u, 0u, 0u};
            }
            *(uint4*)(pan + kt * 8192 + lhi * 256) = o;
        }
    }
    if (blockIdx.x < C_PAD / 256) {
        const int i = blockIdx.x * 256 + tid;
        bias_pad[i] = (i < C_CLS) ? bias[i] : -1e30f;
    }
}

// ---- 128x128 fp8 flat-MFMA GEMM: direct global->reg fragments, no LDS/barriers in K-loop ----
__global__ __launch_bounds__(256, 3)
void gemm_kernel(const int* __restrict__ labels, const float* __restrict__ biasp,
                 const char* __restrict__ A_pre, const char* __restrict__ B_pre,
                 float* __restrict__ s_part, float* __restrict__ tl_part)
{
    __shared__ float red2[128][2][2];

    const int cpx = gridDim.x >> 3;                 // XCD swizzle: same-XCD blocks share rb
    const int wg = (blockIdx.x & 7) * cpx + (blockIdx.x >> 3);
    const int cbp = wg & 15;
    const int rb  = wg >> 4;

    const int tid = threadIdx.x;
    const int w = tid >> 6, lane = tid & 63;
    const int l15 = lane & 15, lhi = lane >> 4;
    const int wr = w >> 1, wcl = w & 1;

    const char* Apan = A_pre + (size_t)rb  * PANEL_B + wr  * 4096 + lane * 16;
    const char* Bpan = B_pre + (size_t)cbp * PANEL_B + wcl * 4096 + lane * 16;

    f32x4 acc[4][4];
    #pragma unroll
    for (int mi = 0; mi < 4; ++mi)
        #pragma unroll
        for (int ni = 0; ni < 4; ++ni) acc[mi][ni] = (f32x4){0.f, 0.f, 0.f, 0.f};

    i64x2 aE[4], bE[4], aO[4], bO[4];

#define LOADT(SA, SB, KTT) do {                                                       \
    const char* pa_ = Apan + (KTT) * 8192;                                            \
    const char* pb_ = Bpan + (KTT) * 8192;                                            \
    _Pragma("unroll")                                                                 \
    for (int i_ = 0; i_ < 4; ++i_) SA[i_] = *(const i64x2*)(pa_ + i_ * 1024);         \
    _Pragma("unroll")                                                                 \
    for (int i_ = 0; i_ < 4; ++i_) SB[i_] = *(const i64x2*)(pb_ + i_ * 1024);         \
} while (0)

#define MFMA32(SA, SB) do {                                                           \
    __builtin_amdgcn_s_setprio(1);                                                    \
    _Pragma("unroll")                                                                 \
    for (int kf_ = 0; kf_ < 2; ++kf_)                                                 \
        _Pragma("unroll")                                                             \
        for (int mi_ = 0; mi_ < 4; ++mi_)                                             \
            _Pragma("unroll")                                                         \
            for (int ni_ = 0; ni_ < 4; ++ni_)                                         \
                acc[mi_][ni_] = __builtin_amdgcn_mfma_f32_16x16x32_fp8_fp8(           \
                    SA[mi_][kf_], SB[ni_][kf_], acc[mi_][ni_], 0, 0, 0);              \
    __builtin_amdgcn_s_setprio(0);                                                    \
} while (0)

#define FENCE __builtin_amdgcn_sched_barrier(0)

    LOADT(aE, bE, 0);
    FENCE;
    #pragma unroll 1
    for (int k2 = 0; k2 < 7; ++k2) {
        LOADT(aO, bO, 2 * k2 + 1);      // issue next-tile loads first (latency cover)
        FENCE;
        MFMA32(aE, bE);                  // compiler inserts counted vmcnt before O-use
        FENCE;
        LOADT(aE, bE, 2 * k2 + 2);
        FENCE;
        MFMA32(aO, bO);
        FENCE;
    }
    LOADT(aO, bO, 15);
    FENCE;
    MFMA32(aE, bE);                      // tile 14
    MFMA32(aO, bO);                      // tile 15

#undef LOADT
#undef MFMA32
#undef FENCE

    // epilogue: rescale + direct sum-exp (logits ~N(0,1); no max needed in fp32)
    float bb[4];
    #pragma unroll
    for (int ni = 0; ni < 4; ++ni)
        bb[ni] = biasp[cbp * 128 + wcl * 64 + ni * 16 + l15];

    #pragma unroll
    for (int mi = 0; mi < 4; ++mi) {
        #pragma unroll
        for (int j = 0; j < 4; ++j) {
            const int rl = wr * 64 + mi * 16 + lhi * 4 + j;
            const int lab = labels[rb * 128 + rl];
            float sv = 0.f, tv = 0.f;
            #pragma unroll
            for (int ni = 0; ni < 4; ++ni) {
                const float v = fmaf(acc[mi][ni][j], INV_SCALE, bb[ni]);
                sv += __expf(v);
                const int gc = cbp * 128 + wcl * 64 + ni * 16 + l15;
                tv = (gc == lab) ? v : tv;
            }
            #pragma unroll
            for (int d = 1; d < 16; d <<= 1) {
                sv += __shfl_xor(sv, d);
                tv += __shfl_xor(tv, d);
            }
            if (l15 == 0) { red2[rl][wcl][0] = sv; red2[rl][wcl][1] = tv; }
        }
    }
    __syncthreads();
    if (tid < 128) {
        const float sv = red2[tid][0][0] + red2[tid][1][0];
        const float tv = red2[tid][0][1] + red2[tid][1][1];
        const int grow = rb * 128 + tid;
        s_part[(size_t)cbp * B_ROWS + grow]  = sv;
        tl_part[(size_t)cbp * B_ROWS + grow] = tv;
    }
}

// ---- combine partials across the 16 column panels, per-row aux loss ----
__global__ __launch_bounds__(256)
void rowcomb_kernel(const float* __restrict__ s_part, const float* __restrict__ tl_part,
                    float* __restrict__ aux_part)
{
    const int row = blockIdx.x * 256 + threadIdx.x;
    float s = 0.f, t = 0.f;
    #pragma unroll
    for (int p = 0; p < NCBP; ++p) {
        s += s_part[(size_t)p * B_ROWS + row];
        t += tl_part[(size_t)p * B_ROWS + row];
    }
    float acc = __logf(s) - t;
    for (int d = 32; d >= 1; d >>= 1) acc += __shfl_xor(acc, d);
    __shared__ float red[4];
    const int wid = threadIdx.x >> 6, lane = threadIdx.x & 63;
    if (lane == 0) red[wid] = acc;
    __syncthreads();
    if (threadIdx.x == 0) aux_part[blockIdx.x] = red[0] + red[1] + red[2] + red[3];
}

__global__ __launch_bounds__(256)
void final_kernel(const float* __restrict__ fisher_part, const float* __restrict__ aux_part,
                  float* __restrict__ out)
{
    const int tid = threadIdx.x;
    float acc = fisher_part[tid] + fisher_part[256 + tid];
    if (tid < 64) acc += aux_part[tid];
    for (int d = 32; d >= 1; d >>= 1) acc += __shfl_xor(acc, d);
    __shared__ float red[4];
    const int wid = tid >> 6, lane = tid & 63;
    if (lane == 0) red[wid] = acc;
    __syncthreads();
    if (tid == 0) out[0] = (red[0] + red[1] + red[2] + red[3]) * (1.0f / (float)B_ROWS);
}

extern "C" void kernel_launch(void* const* d_in, const int* in_sizes, int n_in,
                              void* d_out, int out_size, void* d_ws, size_t ws_size,
                              hipStream_t stream)
{
    (void)in_sizes; (void)n_in; (void)out_size; (void)ws_size;
    const float* feat    = (const float*)d_in[0];
    const int*   labels  = (const int*)  d_in[1];
    const float* centers = (const float*)d_in[2];
    const float* W       = (const float*)d_in[3];
    const float* bias    = (const float*)d_in[4];
    float* out = (float*)d_out;
    char* ws = (char*)d_ws;

    const size_t szA    = (size_t)NRB  * PANEL_B;  // 16,777,216
    const size_t szB    = (size_t)NCBP * PANEL_B;  //  2,097,152
    const size_t szBias = (size_t)C_PAD * 4;

    char* A_pre = ws;
    char* B_pre = ws + szA;
    float* bias_pad    = (float*)(ws + szA + szB);
    float* s_part      = (float*)(ws + szA + szB + szBias);
    float* tl_part     = s_part + (size_t)NCBP * B_ROWS;
    float* fisher_part = tl_part + (size_t)NCBP * B_ROWS;
    float* aux_part    = fisher_part + 512;

    prepA_kernel<<<512, 256, 0, stream>>>(feat, labels, centers, A_pre, fisher_part);
    prepB_kernel<<<128, 256, 0, stream>>>(W, bias, B_pre, bias_pad);
    gemm_kernel<<<NRB * NCBP, 256, 0, stream>>>(labels, bias_pad, A_pre, B_pre, s_part, tl_part);
    rowcomb_kernel<<<B_ROWS / 256, 256, 0, stream>>>(s_part, tl_part, aux_part);
    final_kernel<<<1, 256, 0, stream>>>(fisher_part, aux_part, out);
}

// Round 11
// 80.664 us; speedup vs baseline: 1.2656x; 1.0766x over previous
//
#include <hip/hip_runtime.h>
#include <stdint.h>

#define B_ROWS 16384
#define C_CLS  2000
#define C_PAD  2048
#define F_DIM  1024
#define KT     16                         // K-tiles of 64
#define NRB    64                         // gemm row blocks (256 rows)
#define NCBP   16                         // gemm col panels (128 cols)
#define PANEL_A 262144                    // 16 kt x 16 frags x 1024 B
#define PANEL_BB 131072                   // 16 kt x 8 frags x 1024 B

typedef float f32x4 __attribute__((ext_vector_type(4)));
typedef long long i64x2 __attribute__((ext_vector_type(2)));

#define SCALE_F 4.0f
#define SCALE_W 16.0f
#define INV_SCALE 0.015625f               // 1/64

__device__ __forceinline__ unsigned int pk4(float a, float b, float c, float d) {
    int u = __builtin_amdgcn_cvt_pk_fp8_f32(a, b, 0, false);   // bytes 0,1
    u = __builtin_amdgcn_cvt_pk_fp8_f32(c, d, u, true);        // bytes 2,3
    return (unsigned int)u;
}

// Fragment-linear panels: frag f covers rows f*16..+16; lane l at byte l*16 of the
// 1024B frag; 16B = k[lhi*8..+8) ∪ [32+lhi*8..+8) (i64x2 = [kf0,kf1]) — R10-verified.

// ---- fused prepass: blocks 0..511 = A (feat->fp8 + fisher), 512..639 = B (W->fp8 + bias) ----
__global__ __launch_bounds__(256)
void prep_kernel(const float* __restrict__ feat, const int* __restrict__ labels,
                 const float* __restrict__ centers, const float* __restrict__ W,
                 const float* __restrict__ bias,
                 char* __restrict__ A_pre, char* __restrict__ B_pre,
                 float* __restrict__ bias_pad, float* __restrict__ fisher_part)
{
    const int tid = threadIdx.x;
    if (blockIdx.x < 512) {
        const int rt = blockIdx.x >> 2, g = blockIdx.x & 3;   // rt: 128-row half-panels
        const int rb = rt >> 1;
        const int r = tid >> 1, h = tid & 1;
        const int grow = rt * 128 + r;
        const int lab = labels[grow];
        const float* frow = feat    + (size_t)grow * F_DIM;
        const float* crow = centers + (size_t)lab  * F_DIM;
        const int frag = (rt & 1) * 8 + (r >> 4);
        char* pan = A_pre + (size_t)rb * PANEL_A + frag * 1024 + (r & 15) * 16;
        float facc = 0.f;
        #pragma unroll
        for (int q = 0; q < 4; ++q) {
            const int kt = g * 4 + q;
            #pragma unroll
            for (int u = 0; u < 2; ++u) {
                const int lhi = h * 2 + u;
                const int k0 = kt * 64 + lhi * 8;
                float4 a0 = *(const float4*)(frow + k0);
                float4 a1 = *(const float4*)(frow + k0 + 4);
                float4 a2 = *(const float4*)(frow + k0 + 32);
                float4 a3 = *(const float4*)(frow + k0 + 36);
                float4 c0 = *(const float4*)(crow + k0);
                float4 c1 = *(const float4*)(crow + k0 + 4);
                float4 c2 = *(const float4*)(crow + k0 + 32);
                float4 c3 = *(const float4*)(crow + k0 + 36);
                float d0 = a0.x-c0.x, d1 = a0.y-c0.y, d2 = a0.z-c0.z, d3 = a0.w-c0.w;
                float d4 = a1.x-c1.x, d5 = a1.y-c1.y, d6 = a1.z-c1.z, d7 = a1.w-c1.w;
                facc += d0*d0 + d1*d1 + d2*d2 + d3*d3 + d4*d4 + d5*d5 + d6*d6 + d7*d7;
                d0 = a2.x-c2.x; d1 = a2.y-c2.y; d2 = a2.z-c2.z; d3 = a2.w-c2.w;
                d4 = a3.x-c3.x; d5 = a3.y-c3.y; d6 = a3.z-c3.z; d7 = a3.w-c3.w;
                facc += d0*d0 + d1*d1 + d2*d2 + d3*d3 + d4*d4 + d5*d5 + d6*d6 + d7*d7;
                uint4 o = { pk4(SCALE_F*a0.x, SCALE_F*a0.y, SCALE_F*a0.z, SCALE_F*a0.w),
                            pk4(SCALE_F*a1.x, SCALE_F*a1.y, SCALE_F*a1.z, SCALE_F*a1.w),
                            pk4(SCALE_F*a2.x, SCALE_F*a2.y, SCALE_F*a2.z, SCALE_F*a2.w),
                            pk4(SCALE_F*a3.x, SCALE_F*a3.y, SCALE_F*a3.z, SCALE_F*a3.w) };
                *(uint4*)(pan + kt * 16384 + lhi * 256) = o;
            }
        }
        for (int d = 32; d >= 1; d >>= 1) facc += __shfl_xor(facc, d);
        __shared__ float redw[4];
        const int wid = tid >> 6, lane = tid & 63;
        if (lane == 0) redw[wid] = facc;
        __syncthreads();
        if (tid == 0) fisher_part[blockIdx.x] = redw[0] + redw[1] + redw[2] + redw[3];
    } else {
        const int b = blockIdx.x - 512;
        const int ct = b >> 3, ktg = b & 7;
        const int rcol = tid >> 1, h = tid & 1;
        const int gc = ct * 128 + rcol;
        char* pan = B_pre + (size_t)ct * PANEL_BB + (rcol >> 4) * 1024 + (rcol & 15) * 16;
        #pragma unroll
        for (int q = 0; q < 2; ++q) {
            const int kt = ktg * 2 + q;
            #pragma unroll
            for (int u = 0; u < 2; ++u) {
                const int lhi = h * 2 + u;
                uint4 o;
                if (gc < C_CLS) {
                    const float* src = W + (size_t)gc * F_DIM + kt * 64 + lhi * 8;
                    float4 a0 = *(const float4*)(src);
                    float4 a1 = *(const float4*)(src + 4);
                    float4 a2 = *(const float4*)(src + 32);
                    float4 a3 = *(const float4*)(src + 36);
                    o = (uint4){ pk4(SCALE_W*a0.x, SCALE_W*a0.y, SCALE_W*a0.z, SCALE_W*a0.w),
                                 pk4(SCALE_W*a1.x, SCALE_W*a1.y, SCALE_W*a1.z, SCALE_W*a1.w),
                                 pk4(SCALE_W*a2.x, SCALE_W*a2.y, SCALE_W*a2.z, SCALE_W*a2.w),
                                 pk4(SCALE_W*a3.x, SCALE_W*a3.y, SCALE_W*a3.z, SCALE_W*a3.w) };
                } else {
                    o = (uint4){0u, 0u, 0u, 0u};
                }
                *(uint4*)(pan + kt * 8192 + lhi * 256) = o;
            }
        }
        if (b < C_PAD / 256) {
            const int i = b * 256 + tid;
            bias_pad[i] = (i < C_CLS) ? bias[i] : -1e30f;
        }
    }
}

// ---- 256x128 fp8 flat-MFMA GEMM: 64x128 per wave, global->reg, zero LDS ----
__global__ __launch_bounds__(256, 2)
void gemm_kernel(const int* __restrict__ labels, const float* __restrict__ biasp,
                 const char* __restrict__ A_pre, const char* __restrict__ B_pre,
                 float* __restrict__ s_part, float* __restrict__ tl_part)
{
    const int cpx = gridDim.x >> 3;                 // XCD swizzle: same-XCD blocks share rb
    const int wg = (blockIdx.x & 7) * cpx + (blockIdx.x >> 3);
    const int cb = wg & 15;
    const int rb = wg >> 4;

    const int tid = threadIdx.x;
    const int w = tid >> 6, lane = tid & 63;
    const int l15 = lane & 15, lhi = lane >> 4;

    const char* Apan = A_pre + (size_t)rb * PANEL_A + w * 4096 + lane * 16;
    const char* Bpan = B_pre + (size_t)cb * PANEL_BB + lane * 16;

    f32x4 acc[4][8];
    #pragma unroll
    for (int mi = 0; mi < 4; ++mi)
        #pragma unroll
        for (int ni = 0; ni < 8; ++ni) acc[mi][ni] = (f32x4){0.f, 0.f, 0.f, 0.f};

    i64x2 aE[4], bE[8], aO[4], bO[8];

#define LOADT(SA, SB, KTT) do {                                                       \
    const char* pa_ = Apan + (KTT) * 16384;                                           \
    const char* pb_ = Bpan + (KTT) * 8192;                                            \
    _Pragma("unroll")                                                                 \
    for (int i_ = 0; i_ < 4; ++i_) SA[i_] = *(const i64x2*)(pa_ + i_ * 1024);         \
    _Pragma("unroll")                                                                 \
    for (int i_ = 0; i_ < 8; ++i_) SB[i_] = *(const i64x2*)(pb_ + i_ * 1024);         \
} while (0)

#define MFMA64(SA, SB) do {                                                           \
    __builtin_amdgcn_s_setprio(1);                                                    \
    _Pragma("unroll")                                                                 \
    for (int kf_ = 0; kf_ < 2; ++kf_)                                                 \
        _Pragma("unroll")                                                             \
        for (int mi_ = 0; mi_ < 4; ++mi_)                                             \
            _Pragma("unroll")                                                         \
            for (int ni_ = 0; ni_ < 8; ++ni_)                                         \
                acc[mi_][ni_] = __builtin_amdgcn_mfma_f32_16x16x32_fp8_fp8(           \
                    SA[mi_][kf_], SB[ni_][kf_], acc[mi_][ni_], 0, 0, 0);              \
    __builtin_amdgcn_s_setprio(0);                                                    \
} while (0)

#define FENCE __builtin_amdgcn_sched_barrier(0)

    LOADT(aE, bE, 0);
    FENCE;
    #pragma unroll 1
    for (int k2 = 0; k2 < 7; ++k2) {
        LOADT(aO, bO, 2 * k2 + 1);      // issue next-tile loads first (latency cover)
        FENCE;
        MFMA64(aE, bE);                  // compiler inserts counted vmcnt before O-use
        FENCE;
        LOADT(aE, bE, 2 * k2 + 2);
        FENCE;
        MFMA64(aO, bO);
        FENCE;
    }
    LOADT(aO, bO, 15);
    FENCE;
    MFMA64(aE, bE);                      // tile 14
    MFMA64(aO, bO);                      // tile 15

#undef LOADT
#undef MFMA64
#undef FENCE

    // epilogue: each wave owns full 128-col rows -> no cross-wave reduce, no LDS
    float bb[8];
    #pragma unroll
    for (int ni = 0; ni < 8; ++ni)
        bb[ni] = biasp[cb * 128 + ni * 16 + l15];

    #pragma unroll
    for (int mi = 0; mi < 4; ++mi) {
        #pragma unroll
        for (int j = 0; j < 4; ++j) {
            const int rl = w * 64 + mi * 16 + lhi * 4 + j;
            const int lab = labels[rb * 256 + rl];
            float sv = 0.f, tv = 0.f;
            #pragma unroll
            for (int ni = 0; ni < 8; ++ni) {
                const float v = fmaf(acc[mi][ni][j], INV_SCALE, bb[ni]);
                sv += __expf(v);
                const int gc = cb * 128 + ni * 16 + l15;
                tv = (gc == lab) ? v : tv;
            }
            #pragma unroll
            for (int d = 1; d < 16; d <<= 1) {
                sv += __shfl_xor(sv, d);
                tv += __shfl_xor(tv, d);
            }
            if (l15 == 0) {
                const int grow = rb * 256 + rl;
                s_part[(size_t)cb * B_ROWS + grow]  = sv;
                tl_part[(size_t)cb * B_ROWS + grow] = tv;
            }
        }
    }
}

// ---- combine partials across the 16 column panels, per-row aux loss ----
__global__ __launch_bounds__(256)
void rowcomb_kernel(const float* __restrict__ s_part, const float* __restrict__ tl_part,
                    float* __restrict__ aux_part)
{
    const int row = blockIdx.x * 256 + threadIdx.x;
    float s = 0.f, t = 0.f;
    #pragma unroll
    for (int p = 0; p < NCBP; ++p) {
        s += s_part[(size_t)p * B_ROWS + row];
        t += tl_part[(size_t)p * B_ROWS + row];
    }
    float acc = __logf(s) - t;
    for (int d = 32; d >= 1; d >>= 1) acc += __shfl_xor(acc, d);
    __shared__ float red[4];
    const int wid = threadIdx.x >> 6, lane = threadIdx.x & 63;
    if (lane == 0) red[wid] = acc;
    __syncthreads();
    if (threadIdx.x == 0) aux_part[blockIdx.x] = red[0] + red[1] + red[2] + red[3];
}

__global__ __launch_bounds__(256)
void final_kernel(const float* __restrict__ fisher_part, const float* __restrict__ aux_part,
                  float* __restrict__ out)
{
    const int tid = threadIdx.x;
    float acc = fisher_part[tid] + fisher_part[256 + tid];
    if (tid < 64) acc += aux_part[tid];
    for (int d = 32; d >= 1; d >>= 1) acc += __shfl_xor(acc, d);
    __shared__ float red[4];
    const int wid = tid >> 6, lane = tid & 63;
    if (lane == 0) red[wid] = acc;
    __syncthreads();
    if (tid == 0) out[0] = (red[0] + red[1] + red[2] + red[3]) * (1.0f / (float)B_ROWS);
}

extern "C" void kernel_launch(void* const* d_in, const int* in_sizes, int n_in,
                              void* d_out, int out_size, void* d_ws, size_t ws_size,
                              hipStream_t stream)
{
    (void)in_sizes; (void)n_in; (void)out_size; (void)ws_size;
    const float* feat    = (const float*)d_in[0];
    const int*   labels  = (const int*)  d_in[1];
    const float* centers = (const float*)d_in[2];
    const float* W       = (const float*)d_in[3];
    const float* bias    = (const float*)d_in[4];
    float* out = (float*)d_out;
    char* ws = (char*)d_ws;

    const size_t szA    = (size_t)NRB  * PANEL_A;   // 16,777,216
    const size_t szB    = (size_t)NCBP * PANEL_BB;  //  2,097,152
    const size_t szBias = (size_t)C_PAD * 4;

    char* A_pre = ws;
    char* B_pre = ws + szA;
    float* bias_pad    = (float*)(ws + szA + szB);
    float* s_part      = (float*)(ws + szA + szB + szBias);
    float* tl_part     = s_part + (size_t)NCBP * B_ROWS;
    float* fisher_part = tl_part + (size_t)NCBP * B_ROWS;
    float* aux_part    = fisher_part + 512;

    prep_kernel<<<640, 256, 0, stream>>>(feat, labels, centers, W, bias,
                                         A_pre, B_pre, bias_pad, fisher_part);
    gemm_kernel<<<NRB * NCBP, 256, 0, stream>>>(labels, bias_pad, A_pre, B_pre, s_part, tl_part);
    rowcomb_kernel<<<B_ROWS / 256, 256, 0, stream>>>(s_part, tl_part, aux_part);
    final_kernel<<<1, 256, 0, stream>>>(fisher_part, aux_part, out);
}